// Round 19
// baseline (66.714 us; speedup 1.0000x reference)
//
#include <hip/hip_runtime.h>
#include <cmath>

#define SS 48
#define S3 110592
#define NB 8
#define CIN 4
#define COUT 4
#define HID 128
#define XT 27
#define NP 20
#define BATCH 4
#define PD 50
#define PD2 2500
#define PD3 125000
#define SLABV 648         // 18*6*6 halo voxels per K-slab
#define SLABS 5184        // shorts per slab = 10368 B

typedef __attribute__((ext_vector_type(8))) short short8;
typedef __attribute__((ext_vector_type(4))) float f32x4;

struct Tables {
    int   pid[64];
    float sgn[64];
};

__device__ __forceinline__ unsigned short bf16_rne(float f) {
    union { float f; unsigned u; } c; c.f = f;
    unsigned r = c.u + 0x7FFF + ((c.u >> 16) & 1);
    return (unsigned short)(r >> 16);
}

__device__ __forceinline__ float gelu_tanh(float v) {
    const float c = 0.7978845608028654f;
    float u = c * (v + 0.044715f * v * v * v);
    return 0.5f * v * (1.0f + tanhf(u));
}

// ---------- Stage 0: zero the padded border of xb ---------------------------
__global__ __launch_bounds__(256)
void border_kernel(unsigned short* __restrict__ xb) {
    int b  = blockIdx.y;
    int pv = blockIdx.x * 256 + threadIdx.x;
    if (pv >= PD3) return;
    int zp = pv / PD2, rem = pv % PD2, yp = rem / PD, xp = rem % PD;
    if (zp == 0 || zp == 49 || yp == 0 || yp == 49 || xp == 0 || xp == 49) {
        short8 z8 = {0, 0, 0, 0, 0, 0, 0, 0};
        short8* dst = (short8*)(xb + ((size_t)b * PD3 + pv) * 32);
        dst[0] = z8; dst[1] = z8; dst[2] = z8; dst[3] = z8;
    }
}

// ---------- Stage 1: interior pack (exact 110592 voxels) + cond partials ----
__global__ __launch_bounds__(256)
void pack_cond_kernel(const float* __restrict__ x, unsigned short* __restrict__ xb,
                      float* __restrict__ partial) {
    int b = blockIdx.y;
    int v = blockIdx.x * 256 + threadIdx.x;    // 432 blocks * 256 = 110592 exactly
    __shared__ float sacc[8];
    if (threadIdx.x < 8) sacc[threadIdx.x] = 0.0f;
    __syncthreads();
    int z = v / 2304, rem = v % 2304, y = rem / 48, xx = rem % 48;
    float vals[32];
#pragma unroll
    for (int i = 0; i < 4; ++i) {
        const f32x4* p = (const f32x4*)(x + (((size_t)(b * 4 + i)) * S3 + v) * 8);
        f32x4 a = p[0], c4 = p[1];
        vals[i * 8 + 0] = a[0];  vals[i * 8 + 1] = a[1];
        vals[i * 8 + 2] = a[2];  vals[i * 8 + 3] = a[3];
        vals[i * 8 + 4] = c4[0]; vals[i * 8 + 5] = c4[1];
        vals[i * 8 + 6] = c4[2]; vals[i * 8 + 7] = c4[3];
    }
    float acc[8];
    int dx = 2 * xx - 47, dy = 2 * y - 47, dz = 2 * z - 47;
    bool inmask = (dx * dx + dy * dy + dz * dz <= 2209);
#pragma unroll
    for (int n = 0; n < 8; ++n)
        acc[n] = inmask ? (vals[n] + vals[8 + n] + vals[16 + n] + vals[24 + n]) : 0.0f;

    short8* dst = (short8*)(xb + ((size_t)b * PD3 + (size_t)(z + 1) * PD2 + (y + 1) * PD + (xx + 1)) * 32);
#pragma unroll
    for (int q = 0; q < 4; ++q) {
        short8 s;
#pragma unroll
        for (int e = 0; e < 8; ++e) s[e] = (short)bf16_rne(vals[q * 8 + e]);
        dst[q] = s;
    }
#pragma unroll
    for (int n = 0; n < 8; ++n) {
        float a = acc[n];
        for (int off = 32; off; off >>= 1) a += __shfl_down(a, off);
        if ((threadIdx.x & 63) == 0) atomicAdd(&sacc[n], a);
    }
    __syncthreads();
    if (threadIdx.x < 8)
        partial[((size_t)b * 512 + blockIdx.x) * 8 + threadIdx.x] = sacc[threadIdx.x];
}

// ---------- Stage 2: fused cond-reduce + 3-layer MLP + Cayley assembly ------
__global__ __launch_bounds__(320)
void mlp_fused(const float* __restrict__ partial,
               const float* __restrict__ w0, const float* __restrict__ b0,
               const float* __restrict__ w1, const float* __restrict__ b1,
               const float* __restrict__ w2, const float* __restrict__ b2,
               unsigned short* __restrict__ wb, float inv_norm, Tables tb) {
    int bx = blockIdx.x;
    int b = bx / XT, tap = bx % XT;
    int t = threadIdx.x;
    __shared__ float red[40][8];
    __shared__ float feat[16];
    __shared__ float h1[HID];
    __shared__ float h2[HID];
    __shared__ float wrow[320];
    {
        int ch = t & 7, seg = t >> 3;     // 40 segs
        float s = 0.0f;
        for (int j = seg; j < 432; j += 40)
            s += partial[((size_t)b * 512 + j) * 8 + ch];
        red[seg][ch] = s;
    }
    __syncthreads();
    if (t < 8) {
        float s2 = 0.0f;
#pragma unroll
        for (int q = 0; q < 40; ++q) s2 += red[q][t];
        feat[8 + t] = s2 * inv_norm;
        float v = 0.0f;
        if (t == 1) v = (float)(tap / 9) - 1.0f;
        else if (t == 2) v = (float)((tap / 3) % 3) - 1.0f;
        else if (t == 3) v = (float)(tap % 3) - 1.0f;
        feat[t] = v;
    }
    __syncthreads();
    if (t < 128) {
        float s = b0[t];
#pragma unroll
        for (int k = 0; k < 16; ++k) s += feat[k] * w0[k * HID + t];
        h1[t] = gelu_tanh(s);
    }
    __syncthreads();
    if (t < 128) {
        float a0 = b1[t], a1 = 0.0f, a2 = 0.0f, a3 = 0.0f;
#pragma unroll
        for (int k = 0; k < HID; k += 4) {
            a0 += h1[k + 0] * w1[(k + 0) * HID + t];
            a1 += h1[k + 1] * w1[(k + 1) * HID + t];
            a2 += h1[k + 2] * w1[(k + 2) * HID + t];
            a3 += h1[k + 3] * w1[(k + 3) * HID + t];
        }
        h2[t] = gelu_tanh((a0 + a1) + (a2 + a3));
    }
    __syncthreads();
    {
        float a0 = b2[t], a1 = 0.0f, a2 = 0.0f, a3 = 0.0f;
#pragma unroll
        for (int k = 0; k < HID; k += 4) {
            a0 += h2[k + 0] * w2[(size_t)(k + 0) * 320 + t];
            a1 += h2[k + 1] * w2[(size_t)(k + 1) * 320 + t];
            a2 += h2[k + 2] * w2[(size_t)(k + 2) * 320 + t];
            a3 += h2[k + 3] * w2[(size_t)(k + 3) * 320 + t];
        }
        wrow[t] = (a0 + a1) + (a2 + a3);
    }
    __syncthreads();
    if (t < 128) {
        int m = t >> 2, cq = t & 3;
        int o = m >> 3, bk = m & 7;
        short8 sv;
#pragma unroll
        for (int e = 0; e < 8; ++e) {
            int c = cq * 8 + e;
            int i = c >> 3, bj = c & 7, jk = bj * 8 + bk;
            sv[e] = (short)bf16_rne(tb.sgn[jk] * wrow[o * 80 + i * 20 + tb.pid[jk]]);
        }
        int g  = (tap / 9) * 3 + (tap % 3);   // kz*3 + kx
        int ky = (tap % 9) / 3;
        int half = m >> 4, mm = m & 15;
        size_t tile = (size_t)(b * 27 + g * 3 + ky) * 1024;
        *(short8*)(wb + tile + half * 512 + (mm + cq * 16) * 8) = sv;
    }
}

// ---------- Stage 3: conv — persistent, W resident (no VGPR cap), bfv dbuf --
// 256 blocks x 512 thr (1 block/CU, LDS 82944 B). wave = (zs, mh) specialist.
// launch_bounds(512,1): VGPR cap 256 so wreg[27] (108 VGPR) stays resident.
// Tile loop: stage(t+1) -> compute(t) with bfv prefetched one (kz,kx)-group
// ahead (static even/odd reg buffers) + setprio around MFMA clusters.
__global__ __launch_bounds__(512, 1)
void conv_lds(const unsigned short* __restrict__ xb, const unsigned short* __restrict__ wb,
              const float* __restrict__ bias, float* __restrict__ out) {
    __shared__ __align__(16) short lds[2][4 * SLABS];   // 82944 B
    int bid = blockIdx.x;
    int tid = threadIdx.x, lane = tid & 63, wave = tid >> 6;
    int zs = wave >> 1, mh = wave & 1;
    int col = lane & 15, kl = lane >> 4;

    int b = bid >> 6, k = bid & 63;
    int start, cntt;
    if (k < 48) { start = k * 7; cntt = 7; }
    else        { start = 336 + (k - 48) * 6; cntt = 6; }

    const unsigned short* xbb = xb + (size_t)b * PD3 * 32;

    // ---- W prologue: 27 taps for this mh, asm-forced resident ----
    const unsigned short* wgl = wb + (size_t)b * 27648 + mh * 512 + lane * 8;
    short8 wreg[27];
#pragma unroll
    for (int t27 = 0; t27 < 27; ++t27) {
        const unsigned short* p = wgl + (size_t)t27 * 1024;
        asm volatile("global_load_dwordx4 %0, %1, off" : "=v"(wreg[t27]) : "v"(p));
    }

    // staging: 8 waves cover the 2592 16B-chunks (wave: slab w>>1, half w&1)
    int sl = wave >> 1, hbase = (wave & 1) * 324;
    auto stage = [&](int tau, int buf) {
        int txx = tau % 3, tyy = (tau / 3) % 12, tzz = tau / 36;
        const unsigned short* base = xbb +
            ((size_t)(tzz * 4) * PD2 + (size_t)(tyy * 4) * PD + txx * 16) * 32 + sl * 8;
#pragma unroll
        for (int kk = 0; kk < 6; ++kk) {
            int h0 = hbase + kk * 64;
            int h  = h0 + lane;
            if (h < hbase + 324) {
                int hz = h / 108, rem = h % 108, hy = rem / 18, hx = rem % 18;
                __builtin_amdgcn_global_load_lds(
                    (const unsigned int*)(base + ((size_t)hz * PD2 + hy * PD + hx) * 32),
                    (unsigned int*)&lds[buf][sl * SLABS + h0 * 8], 16, 0, 0);
            }
        }
    };

    stage(start, 0);
    __syncthreads();    // drains W loads + stage0

    for (int i = 0; i < cntt; ++i) {
        int tau = start + i;
        if (i + 1 < cntt) stage(tau + 1, (i + 1) & 1);

        int txx = tau % 3, tyy = (tau / 3) % 12, tzz = tau / 36;
        const short* lbase = &lds[i & 1][kl * SLABS + (zs * 108 + col) * 8];

        f32x4 acc[4];
#pragma unroll
        for (int r = 0; r < 4; ++r)
#pragma unroll
            for (int e = 0; e < 4; ++e) acc[r][e] = 0.0f;

        short8 bfA[6], bfB[6];
#pragma unroll
        for (int u = 0; u < 6; ++u)
            bfA[u] = *(const short8*)(lbase + u * 144);     // group 0 (kz=0,kx=0)

#pragma unroll
        for (int g = 0; g < 9; ++g) {
            const int kzn = (g + 1) / 3, kxn = (g + 1) % 3;
            if ((g & 1) == 0) {
                if (g < 8) {
                    const short* lb = lbase + (kzn * 108 + kxn) * 8;
#pragma unroll
                    for (int u = 0; u < 6; ++u)
                        bfB[u] = *(const short8*)(lb + u * 144);
                }
                __builtin_amdgcn_s_setprio(1);
#pragma unroll
                for (int ky = 0; ky < 3; ++ky) {
                    short8 a = wreg[g * 3 + ky];
#pragma unroll
                    for (int r = 0; r < 4; ++r)
                        acc[r] = __builtin_amdgcn_mfma_f32_16x16x32_bf16(a, bfA[r + ky], acc[r], 0, 0, 0);
                }
                __builtin_amdgcn_s_setprio(0);
            } else {
                if (g < 8) {
                    const short* lb = lbase + (kzn * 108 + kxn) * 8;
#pragma unroll
                    for (int u = 0; u < 6; ++u)
                        bfA[u] = *(const short8*)(lb + u * 144);
                }
                __builtin_amdgcn_s_setprio(1);
#pragma unroll
                for (int ky = 0; ky < 3; ++ky) {
                    short8 a = wreg[g * 3 + ky];
#pragma unroll
                    for (int r = 0; r < 4; ++r)
                        acc[r] = __builtin_amdgcn_mfma_f32_16x16x32_bf16(a, bfB[r + ky], acc[r], 0, 0, 0);
                }
                __builtin_amdgcn_s_setprio(0);
            }
        }

        int xc = txx * 16 + col;
        int z  = tzz * 4 + zs;
        int m0 = kl * 4 + mh * 16;
        int o = m0 >> 3, bk0 = m0 & 7;
        float bi = (bk0 == 0) ? bias[o] : 0.0f;
#pragma unroll
        for (int r = 0; r < 4; ++r) {
            int y = tyy * 4 + r;
            int vox = (z * 48 + y) * 48 + xc;
            f32x4 v = acc[r];
            v[0] += bi;
            *(f32x4*)(out + (((size_t)(b * 4 + o)) * S3 + vox) * 8 + bk0) = v;
        }
        __syncthreads();   // vmcnt(0) here drains next-tile stage (flew during compute)
    }
}

// ---------------- host ------------------------------------------------------
static inline int pc_host(int v) { return __builtin_popcount(v); }

extern "C" void kernel_launch(void* const* d_in, const int* in_sizes, int n_in,
                              void* d_out, int out_size, void* d_ws, size_t ws_size,
                              hipStream_t stream) {
    const float* x    = (const float*)d_in[0];
    const float* w0   = (const float*)d_in[1];
    const float* b0   = (const float*)d_in[2];
    const float* w1   = (const float*)d_in[3];
    const float* b1   = (const float*)d_in[4];
    const float* w2   = (const float*)d_in[5];
    const float* b2   = (const float*)d_in[6];
    const float* bias = (const float*)d_in[7];
    float* out = (float*)d_out;

    float* ws      = (float*)d_ws;
    float* partial = ws;                                     // 16384 floats
    unsigned short* wbb = (unsigned short*)(ws + 30272);     // bf16 W, 110592 shorts
    unsigned short* xb  = wbb + 110592;                      // padded bf16 x, 32 MB

    int cnt = 0;
    for (int z = 0; z < SS; ++z) {
        int dz = 2 * z - 47;
        for (int y = 0; y < SS; ++y) {
            int dy = 2 * y - 47;
            for (int xx = 0; xx < SS; ++xx) {
                int dx = 2 * xx - 47;
                if (dx * dx + dy * dy + dz * dz <= 2209) ++cnt;
            }
        }
    }
    float inv_norm = 1.0f / ((float)cnt * (float)CIN);

    int pidtab[4][4][4];
    {
        bool ex[4][4][4] = {};
        for (int A = 0; A < 8; ++A)
            for (int B = 0; B < 8; ++B)
                ex[pc_host(A)][pc_host(B)][pc_host(A ^ B)] = true;
        int p = 0;
        for (int gi = 0; gi < 4; ++gi)
            for (int gj = 0; gj < 4; ++gj)
                for (int gk = 0; gk < 4; ++gk)
                    pidtab[gi][gj][gk] = ex[gi][gj][gk] ? p++ : -1;
    }
    static const int blades[8] = {0, 1, 2, 4, 3, 5, 6, 7};
    Tables tb;
    for (int bj = 0; bj < 8; ++bj) {
        for (int bk = 0; bk < 8; ++bk) {
            int bmj = blades[bj], bmk = blades[bk];
            int bma = bmj ^ bmk;
            int sgn = 1, t = bma >> 1;
            while (t) {
                if (pc_host(t & bmj) & 1) sgn = -sgn;
                t >>= 1;
            }
            tb.sgn[bj * 8 + bk] = (float)sgn;
            tb.pid[bj * 8 + bk] = pidtab[pc_host(bma)][pc_host(bmj)][pc_host(bmk)];
        }
    }

    border_kernel<<<dim3(489, BATCH), dim3(256), 0, stream>>>(xb);
    pack_cond_kernel<<<dim3(432, BATCH), dim3(256), 0, stream>>>(x, xb, partial);
    mlp_fused<<<dim3(BATCH * XT), dim3(320), 0, stream>>>(partial, w0, b0, w1, b1, w2, b2,
                                                          wbb, inv_norm, tb);
    conv_lds<<<dim3(256), dim3(512), 0, stream>>>(xb, wbb, bias, out);
}

// Round 20
// 65.212 us; speedup vs baseline: 1.0230x; 1.0230x over previous
//
#include <hip/hip_runtime.h>
#include <cmath>

#define SS 48
#define S3 110592
#define NB 8
#define CIN 4
#define COUT 4
#define HID 128
#define XT 27
#define NP 20
#define BATCH 4
#define PD 50
#define PD2 2500
#define PD3 125000
#define SLABV 648         // 18*6*6 halo voxels per K-slab
#define SLABS 5184        // shorts per slab = 10368 B

typedef __attribute__((ext_vector_type(8))) short short8;
typedef __attribute__((ext_vector_type(4))) float f32x4;

struct Tables {
    int   pid[64];
    float sgn[64];
};

__device__ __forceinline__ unsigned short bf16_rne(float f) {
    union { float f; unsigned u; } c; c.f = f;
    unsigned r = c.u + 0x7FFF + ((c.u >> 16) & 1);
    return (unsigned short)(r >> 16);
}

__device__ __forceinline__ float gelu_tanh(float v) {
    const float c = 0.7978845608028654f;
    float u = c * (v + 0.044715f * v * v * v);
    return 0.5f * v * (1.0f + tanhf(u));
}

// ---------- Stage 1: pack x -> padded bf16 + cond partials ------------------
__global__ __launch_bounds__(256)
void pack_cond_kernel(const float* __restrict__ x, unsigned short* __restrict__ xb,
                      float* __restrict__ partial) {
    int b  = blockIdx.y;
    int pv = blockIdx.x * 256 + threadIdx.x;
    __shared__ float sacc[8];
    if (threadIdx.x < 8) sacc[threadIdx.x] = 0.0f;
    __syncthreads();
    float acc[8];
#pragma unroll
    for (int n = 0; n < 8; ++n) acc[n] = 0.0f;
    if (pv < PD3) {
        int zp = pv / PD2, rem = pv % PD2, yp = rem / PD, xp = rem % PD;
        int z = zp - 1, y = yp - 1, xx = xp - 1;
        unsigned short ob[32];
        bool interior = (unsigned)z < 48u && (unsigned)y < 48u && (unsigned)xx < 48u;
        if (interior) {
            int v = (z * 48 + y) * 48 + xx;
            float vals[32];
#pragma unroll
            for (int i = 0; i < 4; ++i) {
                const f32x4* p = (const f32x4*)(x + (((size_t)(b * 4 + i)) * S3 + v) * 8);
                f32x4 a = p[0], c4 = p[1];
                vals[i * 8 + 0] = a[0];  vals[i * 8 + 1] = a[1];
                vals[i * 8 + 2] = a[2];  vals[i * 8 + 3] = a[3];
                vals[i * 8 + 4] = c4[0]; vals[i * 8 + 5] = c4[1];
                vals[i * 8 + 6] = c4[2]; vals[i * 8 + 7] = c4[3];
            }
            int dx = 2 * xx - 47, dy = 2 * y - 47, dz = 2 * z - 47;
            if (dx * dx + dy * dy + dz * dz <= 2209) {
#pragma unroll
                for (int n = 0; n < 8; ++n)
                    acc[n] = vals[n] + vals[8 + n] + vals[16 + n] + vals[24 + n];
            }
#pragma unroll
            for (int k = 0; k < 32; ++k) ob[k] = bf16_rne(vals[k]);
        } else {
#pragma unroll
            for (int k = 0; k < 32; ++k) ob[k] = 0;
        }
        short8* dst = (short8*)(xb + ((size_t)b * PD3 + pv) * 32);
#pragma unroll
        for (int q = 0; q < 4; ++q) {
            short8 s;
#pragma unroll
            for (int e = 0; e < 8; ++e) s[e] = (short)ob[q * 8 + e];
            dst[q] = s;
        }
    }
#pragma unroll
    for (int n = 0; n < 8; ++n) {
        float a = acc[n];
        for (int off = 32; off; off >>= 1) a += __shfl_down(a, off);
        if ((threadIdx.x & 63) == 0) atomicAdd(&sacc[n], a);
    }
    __syncthreads();
    if (threadIdx.x < 8)
        partial[((size_t)b * 512 + blockIdx.x) * 8 + threadIdx.x] = sacc[threadIdx.x];
}

// ---------- Stage 2: fused cond-reduce + 3-layer MLP + Cayley assembly ------
__global__ __launch_bounds__(320)
void mlp_fused(const float* __restrict__ partial,
               const float* __restrict__ w0, const float* __restrict__ b0,
               const float* __restrict__ w1, const float* __restrict__ b1,
               const float* __restrict__ w2, const float* __restrict__ b2,
               unsigned short* __restrict__ wb, float inv_norm, Tables tb) {
    int bx = blockIdx.x;
    int b = bx / XT, tap = bx % XT;
    int t = threadIdx.x;
    __shared__ float red[40][8];
    __shared__ float feat[16];
    __shared__ float h1[HID];
    __shared__ float h2[HID];
    __shared__ float wrow[320];
    {
        int ch = t & 7, seg = t >> 3;     // 40 segs
        float s = 0.0f;
        for (int j = seg; j < 489; j += 40)
            s += partial[((size_t)b * 512 + j) * 8 + ch];
        red[seg][ch] = s;
    }
    __syncthreads();
    if (t < 8) {
        float s2 = 0.0f;
#pragma unroll
        for (int q = 0; q < 40; ++q) s2 += red[q][t];
        feat[8 + t] = s2 * inv_norm;
        float v = 0.0f;
        if (t == 1) v = (float)(tap / 9) - 1.0f;
        else if (t == 2) v = (float)((tap / 3) % 3) - 1.0f;
        else if (t == 3) v = (float)(tap % 3) - 1.0f;
        feat[t] = v;
    }
    __syncthreads();
    if (t < 128) {
        float s = b0[t];
#pragma unroll
        for (int k = 0; k < 16; ++k) s += feat[k] * w0[k * HID + t];
        h1[t] = gelu_tanh(s);
    }
    __syncthreads();
    if (t < 128) {
        float a0 = b1[t], a1 = 0.0f, a2 = 0.0f, a3 = 0.0f;
#pragma unroll
        for (int k = 0; k < HID; k += 4) {
            a0 += h1[k + 0] * w1[(k + 0) * HID + t];
            a1 += h1[k + 1] * w1[(k + 1) * HID + t];
            a2 += h1[k + 2] * w1[(k + 2) * HID + t];
            a3 += h1[k + 3] * w1[(k + 3) * HID + t];
        }
        h2[t] = gelu_tanh((a0 + a1) + (a2 + a3));
    }
    __syncthreads();
    {
        float a0 = b2[t], a1 = 0.0f, a2 = 0.0f, a3 = 0.0f;
#pragma unroll
        for (int k = 0; k < HID; k += 4) {
            a0 += h2[k + 0] * w2[(size_t)(k + 0) * 320 + t];
            a1 += h2[k + 1] * w2[(size_t)(k + 1) * 320 + t];
            a2 += h2[k + 2] * w2[(size_t)(k + 2) * 320 + t];
            a3 += h2[k + 3] * w2[(size_t)(k + 3) * 320 + t];
        }
        wrow[t] = (a0 + a1) + (a2 + a3);
    }
    __syncthreads();
    if (t < 128) {
        int m = t >> 2, cq = t & 3;
        int o = m >> 3, bk = m & 7;
        short8 sv;
#pragma unroll
        for (int e = 0; e < 8; ++e) {
            int c = cq * 8 + e;
            int i = c >> 3, bj = c & 7, jk = bj * 8 + bk;
            sv[e] = (short)bf16_rne(tb.sgn[jk] * wrow[o * 80 + i * 20 + tb.pid[jk]]);
        }
        int g  = (tap / 9) * 3 + (tap % 3);   // kz*3 + kx
        int ky = (tap % 9) / 3;
        int half = m >> 4, mm = m & 15;
        size_t tile = (size_t)(b * 27 + g * 3 + ky) * 1024;
        *(short8*)(wb + tile + half * 512 + (mm + cq * 16) * 8) = sv;
    }
}

// ---------- Stage 3: conv — persistent, W resident, triple-buffer + raw bar -
// 256 blocks x 512 thr (1 block/CU, LDS 124416 B). wave = (zs, mh) specialist.
// x staged into 3 rotating buffers; NO vmcnt(0) in the loop: each iteration
// waits vmcnt(14) (own oldest stage done; next-next stage + last stores may
// stay in flight), then RAW s_barrier (wait-then-barrier => all waves' oldest
// stages done), sched_barrier fence, then stage(t+2) + compute(t) + stores.
__global__ __launch_bounds__(512, 1)
void conv_lds(const unsigned short* __restrict__ xb, const unsigned short* __restrict__ wb,
              const float* __restrict__ bias, float* __restrict__ out) {
    __shared__ __align__(16) short lds[3][4 * SLABS];   // 124416 B
    int bid = blockIdx.x;
    int tid = threadIdx.x, lane = tid & 63, wave = tid >> 6;
    int zs = wave >> 1, mh = wave & 1;
    int col = lane & 15, kl = lane >> 4;

    int b = bid >> 6, k = bid & 63;
    int start, cntt;
    if (k < 48) { start = k * 7; cntt = 7; }
    else        { start = 336 + (k - 48) * 6; cntt = 6; }

    const unsigned short* xbb = xb + (size_t)b * PD3 * 32;

    // ---- W prologue: 27 taps for this mh, asm-forced resident ----
    const unsigned short* wgl = wb + (size_t)b * 27648 + mh * 512 + lane * 8;
    short8 wreg[27];
#pragma unroll
    for (int t27 = 0; t27 < 27; ++t27) {
        const unsigned short* p = wgl + (size_t)t27 * 1024;
        asm volatile("global_load_dwordx4 %0, %1, off" : "=v"(wreg[t27]) : "v"(p));
    }

    // staging: 8 waves cover 2592 16B-chunks (wave: slab w>>1, half w&1); 6 issues
    int sl = wave >> 1, hbase = (wave & 1) * 324;
    auto stage = [&](int tau, int buf) {
        int txx = tau % 3, tyy = (tau / 3) % 12, tzz = tau / 36;
        const unsigned short* base = xbb +
            ((size_t)(tzz * 4) * PD2 + (size_t)(tyy * 4) * PD + txx * 16) * 32 + sl * 8;
#pragma unroll
        for (int kk = 0; kk < 6; ++kk) {
            int h0 = hbase + kk * 64;
            int h  = h0 + lane;
            if (h < hbase + 324) {
                int hz = h / 108, rem = h % 108, hy = rem / 18, hx = rem % 18;
                __builtin_amdgcn_global_load_lds(
                    (const unsigned int*)(base + ((size_t)hz * PD2 + hy * PD + hx) * 32),
                    (unsigned int*)&lds[buf][sl * SLABS + h0 * 8], 16, 0, 0);
            }
        }
    };

    // prologue: stage t0 and t1; one full barrier (also drains W loads)
    stage(start, 0);
    if (cntt > 1) stage(start + 1, 1);
    __syncthreads();

    int curbuf = 0;
    for (int i = 0; i < cntt; ++i) {
        int tau = start + i;
        if (i > 0) {
            // own oldest stage (tile i) done; newer stage + stores may fly
            asm volatile("s_waitcnt vmcnt(14)" ::: "memory");
            __builtin_amdgcn_s_barrier();
            __builtin_amdgcn_sched_barrier(0);
        }
        if (i + 2 < cntt) stage(tau + 2, (curbuf + 2) % 3);

        int txx = tau % 3, tyy = (tau / 3) % 12, tzz = tau / 36;
        const short* lbase = &lds[curbuf][kl * SLABS + (zs * 108 + col) * 8];

        f32x4 acc[4];
#pragma unroll
        for (int r = 0; r < 4; ++r)
#pragma unroll
            for (int e = 0; e < 4; ++e) acc[r][e] = 0.0f;

#pragma unroll
        for (int kz = 0; kz < 3; ++kz)
#pragma unroll
            for (int kx = 0; kx < 3; ++kx) {
                const short* lb = lbase + (kz * 108 + kx) * 8;
                short8 bfv[6];
#pragma unroll
                for (int u = 0; u < 6; ++u)
                    bfv[u] = *(const short8*)(lb + u * 144);
#pragma unroll
                for (int ky = 0; ky < 3; ++ky) {
                    short8 a = wreg[(kz * 3 + kx) * 3 + ky];
#pragma unroll
                    for (int r = 0; r < 4; ++r)
                        acc[r] = __builtin_amdgcn_mfma_f32_16x16x32_bf16(a, bfv[r + ky], acc[r], 0, 0, 0);
                }
            }

        int xc = txx * 16 + col;
        int z  = tzz * 4 + zs;
        int m0 = kl * 4 + mh * 16;
        int o = m0 >> 3, bk0 = m0 & 7;
        float bi = (bk0 == 0) ? bias[o] : 0.0f;
#pragma unroll
        for (int r = 0; r < 4; ++r) {
            int y = tyy * 4 + r;
            int vox = (z * 48 + y) * 48 + xc;
            f32x4 v = acc[r];
            v[0] += bi;
            *(f32x4*)(out + (((size_t)(b * 4 + o)) * S3 + vox) * 8 + bk0) = v;
        }
        curbuf = (curbuf + 1) % 3;
    }
}

// ---------------- host ------------------------------------------------------
static inline int pc_host(int v) { return __builtin_popcount(v); }

extern "C" void kernel_launch(void* const* d_in, const int* in_sizes, int n_in,
                              void* d_out, int out_size, void* d_ws, size_t ws_size,
                              hipStream_t stream) {
    const float* x    = (const float*)d_in[0];
    const float* w0   = (const float*)d_in[1];
    const float* b0   = (const float*)d_in[2];
    const float* w1   = (const float*)d_in[3];
    const float* b1   = (const float*)d_in[4];
    const float* w2   = (const float*)d_in[5];
    const float* b2   = (const float*)d_in[6];
    const float* bias = (const float*)d_in[7];
    float* out = (float*)d_out;

    float* ws      = (float*)d_ws;
    float* partial = ws;                                     // 16384 floats
    unsigned short* wbb = (unsigned short*)(ws + 30272);     // bf16 W, 110592 shorts
    unsigned short* xb  = wbb + 110592;                      // padded bf16 x, 32 MB

    int cnt = 0;
    for (int z = 0; z < SS; ++z) {
        int dz = 2 * z - 47;
        for (int y = 0; y < SS; ++y) {
            int dy = 2 * y - 47;
            for (int xx = 0; xx < SS; ++xx) {
                int dx = 2 * xx - 47;
                if (dx * dx + dy * dy + dz * dz <= 2209) ++cnt;
            }
        }
    }
    float inv_norm = 1.0f / ((float)cnt * (float)CIN);

    int pidtab[4][4][4];
    {
        bool ex[4][4][4] = {};
        for (int A = 0; A < 8; ++A)
            for (int B = 0; B < 8; ++B)
                ex[pc_host(A)][pc_host(B)][pc_host(A ^ B)] = true;
        int p = 0;
        for (int gi = 0; gi < 4; ++gi)
            for (int gj = 0; gj < 4; ++gj)
                for (int gk = 0; gk < 4; ++gk)
                    pidtab[gi][gj][gk] = ex[gi][gj][gk] ? p++ : -1;
    }
    static const int blades[8] = {0, 1, 2, 4, 3, 5, 6, 7};
    Tables tb;
    for (int bj = 0; bj < 8; ++bj) {
        for (int bk = 0; bk < 8; ++bk) {
            int bmj = blades[bj], bmk = blades[bk];
            int bma = bmj ^ bmk;
            int sgn = 1, t = bma >> 1;
            while (t) {
                if (pc_host(t & bmj) & 1) sgn = -sgn;
                t >>= 1;
            }
            tb.sgn[bj * 8 + bk] = (float)sgn;
            tb.pid[bj * 8 + bk] = pidtab[pc_host(bma)][pc_host(bmj)][pc_host(bmk)];
        }
    }

    pack_cond_kernel<<<dim3(489, BATCH), dim3(256), 0, stream>>>(x, xb, partial);
    mlp_fused<<<dim3(BATCH * XT), dim3(320), 0, stream>>>(partial, w0, b0, w1, b1, w2, b2,
                                                          wbb, inv_norm, tb);
    conv_lds<<<dim3(256), dim3(512), 0, stream>>>(xb, wbb, bias, out);
}

// Round 21
// 63.123 us; speedup vs baseline: 1.0569x; 1.0331x over previous
//
#include <hip/hip_runtime.h>
#include <hip/hip_bf16.h>
#include <cmath>

#define SS 48
#define S3 110592
#define NB 8
#define CIN 4
#define COUT 4
#define HID 128
#define XT 27
#define NP 20
#define BATCH 4
#define PD 50
#define PD2 2500
#define PD3 125000
#define SLABV 648         // 18*6*6 halo voxels per K-slab
#define SLABS 5184        // shorts per slab = 10368 B

typedef __attribute__((ext_vector_type(8))) short short8;
typedef __attribute__((ext_vector_type(4))) float f32x4;
typedef __attribute__((ext_vector_type(4))) unsigned int u32x4;

struct Tables {
    int   pid[64];
    float sgn[64];
};

__device__ __forceinline__ unsigned short bf16_rne(float f) {
    union { float f; unsigned u; } c; c.f = f;
    unsigned r = c.u + 0x7FFF + ((c.u >> 16) & 1);
    return (unsigned short)(r >> 16);
}

__device__ __forceinline__ unsigned int pk_bf16(float a, float b) {
    union { __hip_bfloat162 h; unsigned int u; } cv;
    cv.h = __float22bfloat162_rn(float2{a, b});
    return cv.u;
}

__device__ __forceinline__ float gelu_tanh(float v) {
    const float c = 0.7978845608028654f;
    float u = c * (v + 0.044715f * v * v * v);
    return 0.5f * v * (1.0f + tanhf(u));
}

// ---------- Stage 1: pack x -> padded bf16 (HW cvt_pk) + cond partials ------
__global__ __launch_bounds__(256)
void pack_cond_kernel(const float* __restrict__ x, unsigned short* __restrict__ xb,
                      float* __restrict__ partial) {
    int b  = blockIdx.y;
    int pv = blockIdx.x * 256 + threadIdx.x;
    __shared__ float sacc[8];
    if (threadIdx.x < 8) sacc[threadIdx.x] = 0.0f;
    __syncthreads();
    float acc[8];
#pragma unroll
    for (int n = 0; n < 8; ++n) acc[n] = 0.0f;
    if (pv < PD3) {
        int zp = pv / PD2, rem = pv % PD2, yp = rem / PD, xp = rem % PD;
        int z = zp - 1, y = yp - 1, xx = xp - 1;
        unsigned int w[16];
        bool interior = (unsigned)z < 48u && (unsigned)y < 48u && (unsigned)xx < 48u;
        if (interior) {
            int v = (z * 48 + y) * 48 + xx;
            float vals[32];
#pragma unroll
            for (int i = 0; i < 4; ++i) {
                const f32x4* p = (const f32x4*)(x + (((size_t)(b * 4 + i)) * S3 + v) * 8);
                f32x4 a = p[0], c4 = p[1];
                vals[i * 8 + 0] = a[0];  vals[i * 8 + 1] = a[1];
                vals[i * 8 + 2] = a[2];  vals[i * 8 + 3] = a[3];
                vals[i * 8 + 4] = c4[0]; vals[i * 8 + 5] = c4[1];
                vals[i * 8 + 6] = c4[2]; vals[i * 8 + 7] = c4[3];
            }
            int dx = 2 * xx - 47, dy = 2 * y - 47, dz = 2 * z - 47;
            if (dx * dx + dy * dy + dz * dz <= 2209) {
#pragma unroll
                for (int n = 0; n < 8; ++n)
                    acc[n] = vals[n] + vals[8 + n] + vals[16 + n] + vals[24 + n];
            }
#pragma unroll
            for (int p2 = 0; p2 < 16; ++p2)
                w[p2] = pk_bf16(vals[2 * p2], vals[2 * p2 + 1]);
        } else {
#pragma unroll
            for (int p2 = 0; p2 < 16; ++p2) w[p2] = 0u;
        }
        u32x4* dst = (u32x4*)(xb + ((size_t)b * PD3 + pv) * 32);
#pragma unroll
        for (int q = 0; q < 4; ++q) {
            u32x4 s;
#pragma unroll
            for (int e = 0; e < 4; ++e) s[e] = w[q * 4 + e];
            dst[q] = s;
        }
    }
#pragma unroll
    for (int n = 0; n < 8; ++n) {
        float a = acc[n];
        for (int off = 32; off; off >>= 1) a += __shfl_down(a, off);
        if ((threadIdx.x & 63) == 0) atomicAdd(&sacc[n], a);
    }
    __syncthreads();
    if (threadIdx.x < 8)
        partial[((size_t)b * 512 + blockIdx.x) * 8 + threadIdx.x] = sacc[threadIdx.x];
}

// ---------- Stage 2: fused cond-reduce + 3-layer MLP + Cayley assembly ------
__global__ __launch_bounds__(320)
void mlp_fused(const float* __restrict__ partial,
               const float* __restrict__ w0, const float* __restrict__ b0,
               const float* __restrict__ w1, const float* __restrict__ b1,
               const float* __restrict__ w2, const float* __restrict__ b2,
               unsigned short* __restrict__ wb, float inv_norm, Tables tb) {
    int bx = blockIdx.x;
    int b = bx / XT, tap = bx % XT;
    int t = threadIdx.x;
    __shared__ float red[40][8];
    __shared__ float feat[16];
    __shared__ float h1[HID];
    __shared__ float h2[HID];
    __shared__ float wrow[320];
    {
        int ch = t & 7, seg = t >> 3;     // 40 segs
        float s = 0.0f;
        for (int j = seg; j < 489; j += 40)
            s += partial[((size_t)b * 512 + j) * 8 + ch];
        red[seg][ch] = s;
    }
    __syncthreads();
    if (t < 8) {
        float s2 = 0.0f;
#pragma unroll
        for (int q = 0; q < 40; ++q) s2 += red[q][t];
        feat[8 + t] = s2 * inv_norm;
        float v = 0.0f;
        if (t == 1) v = (float)(tap / 9) - 1.0f;
        else if (t == 2) v = (float)((tap / 3) % 3) - 1.0f;
        else if (t == 3) v = (float)(tap % 3) - 1.0f;
        feat[t] = v;
    }
    __syncthreads();
    if (t < 128) {
        float s = b0[t];
#pragma unroll
        for (int k = 0; k < 16; ++k) s += feat[k] * w0[k * HID + t];
        h1[t] = gelu_tanh(s);
    }
    __syncthreads();
    if (t < 128) {
        float a0 = b1[t], a1 = 0.0f, a2 = 0.0f, a3 = 0.0f;
#pragma unroll
        for (int k = 0; k < HID; k += 4) {
            a0 += h1[k + 0] * w1[(k + 0) * HID + t];
            a1 += h1[k + 1] * w1[(k + 1) * HID + t];
            a2 += h1[k + 2] * w1[(k + 2) * HID + t];
            a3 += h1[k + 3] * w1[(k + 3) * HID + t];
        }
        h2[t] = gelu_tanh((a0 + a1) + (a2 + a3));
    }
    __syncthreads();
    {
        float a0 = b2[t], a1 = 0.0f, a2 = 0.0f, a3 = 0.0f;
#pragma unroll
        for (int k = 0; k < HID; k += 4) {
            a0 += h2[k + 0] * w2[(size_t)(k + 0) * 320 + t];
            a1 += h2[k + 1] * w2[(size_t)(k + 1) * 320 + t];
            a2 += h2[k + 2] * w2[(size_t)(k + 2) * 320 + t];
            a3 += h2[k + 3] * w2[(size_t)(k + 3) * 320 + t];
        }
        wrow[t] = (a0 + a1) + (a2 + a3);
    }
    __syncthreads();
    if (t < 128) {
        int m = t >> 2, cq = t & 3;
        int o = m >> 3, bk = m & 7;
        short8 sv;
#pragma unroll
        for (int e = 0; e < 8; ++e) {
            int c = cq * 8 + e;
            int i = c >> 3, bj = c & 7, jk = bj * 8 + bk;
            sv[e] = (short)bf16_rne(tb.sgn[jk] * wrow[o * 80 + i * 20 + tb.pid[jk]]);
        }
        int g  = (tap / 9) * 3 + (tap % 3);   // kz*3 + kx
        int ky = (tap % 9) / 3;
        int half = m >> 4, mm = m & 15;
        size_t tile = (size_t)(b * 27 + g * 3 + ky) * 1024;
        *(short8*)(wb + tile + half * 512 + (mm + cq * 16) * 8) = sv;
    }
}

// ---------- Stage 3: conv — persistent blocks, tile-pipelined LDS dbuf ------
// (exact R18 structure — best measured; 256 blocks x 512 thr, wave=(zs,mh),
// W asm-loaded once, stage(t+1) -> compute(t) -> __syncthreads.)
__global__ __launch_bounds__(512, 2)
void conv_lds(const unsigned short* __restrict__ xb, const unsigned short* __restrict__ wb,
              const float* __restrict__ bias, float* __restrict__ out) {
    __shared__ __align__(16) short lds[2][4 * SLABS];   // 82944 B
    int bid = blockIdx.x;
    int tid = threadIdx.x, lane = tid & 63, wave = tid >> 6;
    int zs = wave >> 1, mh = wave & 1;
    int col = lane & 15, kl = lane >> 4;

    int b = bid >> 6, k = bid & 63;
    int start, cntt;
    if (k < 48) { start = k * 7; cntt = 7; }
    else        { start = 336 + (k - 48) * 6; cntt = 6; }

    const unsigned short* xbb = xb + (size_t)b * PD3 * 32;

    // ---- W prologue: 27 taps for this mh, asm-forced resident ----
    const unsigned short* wgl = wb + (size_t)b * 27648 + mh * 512 + lane * 8;
    short8 wreg[27];
#pragma unroll
    for (int t27 = 0; t27 < 27; ++t27) {
        const unsigned short* p = wgl + (size_t)t27 * 1024;
        asm volatile("global_load_dwordx4 %0, %1, off" : "=v"(wreg[t27]) : "v"(p));
    }

    // staging: 8 waves cover 2592 16B-chunks (wave: slab w>>1, half w&1)
    int sl = wave >> 1, hbase = (wave & 1) * 324;
    auto stage = [&](int tau, int buf) {
        int txx = tau % 3, tyy = (tau / 3) % 12, tzz = tau / 36;
        const unsigned short* base = xbb +
            ((size_t)(tzz * 4) * PD2 + (size_t)(tyy * 4) * PD + txx * 16) * 32 + sl * 8;
#pragma unroll
        for (int kk = 0; kk < 6; ++kk) {
            int h0 = hbase + kk * 64;
            int h  = h0 + lane;
            if (h < hbase + 324) {
                int hz = h / 108, rem = h % 108, hy = rem / 18, hx = rem % 18;
                __builtin_amdgcn_global_load_lds(
                    (const unsigned int*)(base + ((size_t)hz * PD2 + hy * PD + hx) * 32),
                    (unsigned int*)&lds[buf][sl * SLABS + h0 * 8], 16, 0, 0);
            }
        }
    };

    stage(start, 0);
    __syncthreads();    // drains W loads + stage0

    for (int i = 0; i < cntt; ++i) {
        int tau = start + i;
        if (i + 1 < cntt) stage(tau + 1, (i + 1) & 1);

        int txx = tau % 3, tyy = (tau / 3) % 12, tzz = tau / 36;
        const short* lbase = &lds[i & 1][kl * SLABS + (zs * 108 + col) * 8];

        f32x4 acc[4];
#pragma unroll
        for (int r = 0; r < 4; ++r)
#pragma unroll
            for (int e = 0; e < 4; ++e) acc[r][e] = 0.0f;

#pragma unroll
        for (int kz = 0; kz < 3; ++kz)
#pragma unroll
            for (int kx = 0; kx < 3; ++kx) {
                const short* lb = lbase + (kz * 108 + kx) * 8;
                short8 bfv[6];
#pragma unroll
                for (int u = 0; u < 6; ++u)
                    bfv[u] = *(const short8*)(lb + u * 144);
#pragma unroll
                for (int ky = 0; ky < 3; ++ky) {
                    short8 a = wreg[(kz * 3 + kx) * 3 + ky];
#pragma unroll
                    for (int r = 0; r < 4; ++r)
                        acc[r] = __builtin_amdgcn_mfma_f32_16x16x32_bf16(a, bfv[r + ky], acc[r], 0, 0, 0);
                }
            }

        int xc = txx * 16 + col;
        int z  = tzz * 4 + zs;
        int m0 = kl * 4 + mh * 16;
        int o = m0 >> 3, bk0 = m0 & 7;
        float bi = (bk0 == 0) ? bias[o] : 0.0f;
#pragma unroll
        for (int r = 0; r < 4; ++r) {
            int y = tyy * 4 + r;
            int vox = (z * 48 + y) * 48 + xc;
            f32x4 v = acc[r];
            v[0] += bi;
            *(f32x4*)(out + (((size_t)(b * 4 + o)) * S3 + vox) * 8 + bk0) = v;
        }
        __syncthreads();   // vmcnt(0) here drains next-tile stage (flew during compute)
    }
}

// ---------------- host ------------------------------------------------------
static inline int pc_host(int v) { return __builtin_popcount(v); }

extern "C" void kernel_launch(void* const* d_in, const int* in_sizes, int n_in,
                              void* d_out, int out_size, void* d_ws, size_t ws_size,
                              hipStream_t stream) {
    const float* x    = (const float*)d_in[0];
    const float* w0   = (const float*)d_in[1];
    const float* b0   = (const float*)d_in[2];
    const float* w1   = (const float*)d_in[3];
    const float* b1   = (const float*)d_in[4];
    const float* w2   = (const float*)d_in[5];
    const float* b2   = (const float*)d_in[6];
    const float* bias = (const float*)d_in[7];
    float* out = (float*)d_out;

    float* ws      = (float*)d_ws;
    float* partial = ws;                                     // 16384 floats
    unsigned short* wbb = (unsigned short*)(ws + 30272);     // bf16 W, 110592 shorts
    unsigned short* xb  = wbb + 110592;                      // padded bf16 x, 32 MB

    int cnt = 0;
    for (int z = 0; z < SS; ++z) {
        int dz = 2 * z - 47;
        for (int y = 0; y < SS; ++y) {
            int dy = 2 * y - 47;
            for (int xx = 0; xx < SS; ++xx) {
                int dx = 2 * xx - 47;
                if (dx * dx + dy * dy + dz * dz <= 2209) ++cnt;
            }
        }
    }
    float inv_norm = 1.0f / ((float)cnt * (float)CIN);

    int pidtab[4][4][4];
    {
        bool ex[4][4][4] = {};
        for (int A = 0; A < 8; ++A)
            for (int B = 0; B < 8; ++B)
                ex[pc_host(A)][pc_host(B)][pc_host(A ^ B)] = true;
        int p = 0;
        for (int gi = 0; gi < 4; ++gi)
            for (int gj = 0; gj < 4; ++gj)
                for (int gk = 0; gk < 4; ++gk)
                    pidtab[gi][gj][gk] = ex[gi][gj][gk] ? p++ : -1;
    }
    static const int blades[8] = {0, 1, 2, 4, 3, 5, 6, 7};
    Tables tb;
    for (int bj = 0; bj < 8; ++bj) {
        for (int bk = 0; bk < 8; ++bk) {
            int bmj = blades[bj], bmk = blades[bk];
            int bma = bmj ^ bmk;
            int sgn = 1, t = bma >> 1;
            while (t) {
                if (pc_host(t & bmj) & 1) sgn = -sgn;
                t >>= 1;
            }
            tb.sgn[bj * 8 + bk] = (float)sgn;
            tb.pid[bj * 8 + bk] = pidtab[pc_host(bma)][pc_host(bmj)][pc_host(bmk)];
        }
    }

    pack_cond_kernel<<<dim3(489, BATCH), dim3(256), 0, stream>>>(x, xb, partial);
    mlp_fused<<<dim3(BATCH * XT), dim3(320), 0, stream>>>(partial, w0, b0, w1, b1, w2, b2,
                                                          wbb, inv_norm, tb);
    conv_lds<<<dim3(256), dim3(512), 0, stream>>>(xb, wbb, bias, out);
}

// Round 22
// 63.078 us; speedup vs baseline: 1.0576x; 1.0007x over previous
//
#include <hip/hip_runtime.h>
#include <hip/hip_bf16.h>
#include <cmath>

#define SS 48
#define S3 110592
#define NB 8
#define CIN 4
#define COUT 4
#define HID 128
#define XT 27
#define NP 20
#define BATCH 4
#define PD 50
#define PD2 2500
#define PD3 125000
#define SLABV 648         // 18*6*6 halo voxels per K-slab
#define SLABS 5184        // shorts per slab = 10368 B

typedef __attribute__((ext_vector_type(8))) short short8;
typedef __attribute__((ext_vector_type(4))) float f32x4;
typedef __attribute__((ext_vector_type(4))) unsigned int u32x4;

struct Tables {
    int   pid[64];
    float sgn[64];
};

__device__ __forceinline__ unsigned short bf16_rne(float f) {
    union { float f; unsigned u; } c; c.f = f;
    unsigned r = c.u + 0x7FFF + ((c.u >> 16) & 1);
    return (unsigned short)(r >> 16);
}

__device__ __forceinline__ unsigned int pk_bf16(float a, float b) {
    union { __hip_bfloat162 h; unsigned int u; } cv;
    cv.h = __float22bfloat162_rn(float2{a, b});
    return cv.u;
}

__device__ __forceinline__ float gelu_tanh(float v) {
    const float c = 0.7978845608028654f;
    float u = c * (v + 0.044715f * v * v * v);
    return 0.5f * v * (1.0f + tanhf(u));
}

// ---------- Stage 1: pack x -> padded bf16 (HW cvt_pk) + cond partials ------
__global__ __launch_bounds__(256)
void pack_cond_kernel(const float* __restrict__ x, unsigned short* __restrict__ xb,
                      float* __restrict__ partial) {
    int b  = blockIdx.y;
    int pv = blockIdx.x * 256 + threadIdx.x;
    __shared__ float sacc[8];
    if (threadIdx.x < 8) sacc[threadIdx.x] = 0.0f;
    __syncthreads();
    float acc[8];
#pragma unroll
    for (int n = 0; n < 8; ++n) acc[n] = 0.0f;
    if (pv < PD3) {
        int zp = pv / PD2, rem = pv % PD2, yp = rem / PD, xp = rem % PD;
        int z = zp - 1, y = yp - 1, xx = xp - 1;
        unsigned int w[16];
        bool interior = (unsigned)z < 48u && (unsigned)y < 48u && (unsigned)xx < 48u;
        if (interior) {
            int v = (z * 48 + y) * 48 + xx;
            float vals[32];
#pragma unroll
            for (int i = 0; i < 4; ++i) {
                const f32x4* p = (const f32x4*)(x + (((size_t)(b * 4 + i)) * S3 + v) * 8);
                f32x4 a = p[0], c4 = p[1];
                vals[i * 8 + 0] = a[0];  vals[i * 8 + 1] = a[1];
                vals[i * 8 + 2] = a[2];  vals[i * 8 + 3] = a[3];
                vals[i * 8 + 4] = c4[0]; vals[i * 8 + 5] = c4[1];
                vals[i * 8 + 6] = c4[2]; vals[i * 8 + 7] = c4[3];
            }
            int dx = 2 * xx - 47, dy = 2 * y - 47, dz = 2 * z - 47;
            if (dx * dx + dy * dy + dz * dz <= 2209) {
#pragma unroll
                for (int n = 0; n < 8; ++n)
                    acc[n] = vals[n] + vals[8 + n] + vals[16 + n] + vals[24 + n];
            }
#pragma unroll
            for (int p2 = 0; p2 < 16; ++p2)
                w[p2] = pk_bf16(vals[2 * p2], vals[2 * p2 + 1]);
        } else {
#pragma unroll
            for (int p2 = 0; p2 < 16; ++p2) w[p2] = 0u;
        }
        u32x4* dst = (u32x4*)(xb + ((size_t)b * PD3 + pv) * 32);
#pragma unroll
        for (int q = 0; q < 4; ++q) {
            u32x4 s;
#pragma unroll
            for (int e = 0; e < 4; ++e) s[e] = w[q * 4 + e];
            dst[q] = s;
        }
    }
#pragma unroll
    for (int n = 0; n < 8; ++n) {
        float a = acc[n];
        for (int off = 32; off; off >>= 1) a += __shfl_down(a, off);
        if ((threadIdx.x & 63) == 0) atomicAdd(&sacc[n], a);
    }
    __syncthreads();
    if (threadIdx.x < 8)
        partial[((size_t)b * 512 + blockIdx.x) * 8 + threadIdx.x] = sacc[threadIdx.x];
}

// ---------- Stage 2: fused cond-reduce + 3-layer MLP + Cayley assembly ------
__global__ __launch_bounds__(320)
void mlp_fused(const float* __restrict__ partial,
               const float* __restrict__ w0, const float* __restrict__ b0,
               const float* __restrict__ w1, const float* __restrict__ b1,
               const float* __restrict__ w2, const float* __restrict__ b2,
               unsigned short* __restrict__ wb, float inv_norm, Tables tb) {
    int bx = blockIdx.x;
    int b = bx / XT, tap = bx % XT;
    int t = threadIdx.x;
    __shared__ float red[40][8];
    __shared__ float feat[16];
    __shared__ float h1[HID];
    __shared__ float h2[HID];
    __shared__ float wrow[320];
    {
        int ch = t & 7, seg = t >> 3;     // 40 segs
        float s = 0.0f;
        for (int j = seg; j < 489; j += 40)
            s += partial[((size_t)b * 512 + j) * 8 + ch];
        red[seg][ch] = s;
    }
    __syncthreads();
    if (t < 8) {
        float s2 = 0.0f;
#pragma unroll
        for (int q = 0; q < 40; ++q) s2 += red[q][t];
        feat[8 + t] = s2 * inv_norm;
        float v = 0.0f;
        if (t == 1) v = (float)(tap / 9) - 1.0f;
        else if (t == 2) v = (float)((tap / 3) % 3) - 1.0f;
        else if (t == 3) v = (float)(tap % 3) - 1.0f;
        feat[t] = v;
    }
    __syncthreads();
    if (t < 128) {
        float s = b0[t];
#pragma unroll
        for (int k = 0; k < 16; ++k) s += feat[k] * w0[k * HID + t];
        h1[t] = gelu_tanh(s);
    }
    __syncthreads();
    if (t < 128) {
        float a0 = b1[t], a1 = 0.0f, a2 = 0.0f, a3 = 0.0f;
#pragma unroll
        for (int k = 0; k < HID; k += 4) {
            a0 += h1[k + 0] * w1[(k + 0) * HID + t];
            a1 += h1[k + 1] * w1[(k + 1) * HID + t];
            a2 += h1[k + 2] * w1[(k + 2) * HID + t];
            a3 += h1[k + 3] * w1[(k + 3) * HID + t];
        }
        h2[t] = gelu_tanh((a0 + a1) + (a2 + a3));
    }
    __syncthreads();
    {
        float a0 = b2[t], a1 = 0.0f, a2 = 0.0f, a3 = 0.0f;
#pragma unroll
        for (int k = 0; k < HID; k += 4) {
            a0 += h2[k + 0] * w2[(size_t)(k + 0) * 320 + t];
            a1 += h2[k + 1] * w2[(size_t)(k + 1) * 320 + t];
            a2 += h2[k + 2] * w2[(size_t)(k + 2) * 320 + t];
            a3 += h2[k + 3] * w2[(size_t)(k + 3) * 320 + t];
        }
        wrow[t] = (a0 + a1) + (a2 + a3);
    }
    __syncthreads();
    if (t < 128) {
        int m = t >> 2, cq = t & 3;
        int o = m >> 3, bk = m & 7;
        short8 sv;
#pragma unroll
        for (int e = 0; e < 8; ++e) {
            int c = cq * 8 + e;
            int i = c >> 3, bj = c & 7, jk = bj * 8 + bk;
            sv[e] = (short)bf16_rne(tb.sgn[jk] * wrow[o * 80 + i * 20 + tb.pid[jk]]);
        }
        int g  = (tap / 9) * 3 + (tap % 3);   // kz*3 + kx
        int ky = (tap % 9) / 3;
        int half = m >> 4, mm = m & 15;
        size_t tile = (size_t)(b * 27 + g * 3 + ky) * 1024;
        *(short8*)(wb + tile + half * 512 + (mm + cq * 16) * 8) = sv;
    }
}

// ---------- Stage 3: conv — persistent, W resident, store-exempt barrier ----
// R18 structure, but the per-tile __syncthreads is replaced by
// s_waitcnt vmcnt(4) + raw s_barrier: the 6 stage loads (oldest in the VMEM
// FIFO) are retired, the 4 output stores stay in flight across the boundary.
__global__ __launch_bounds__(512, 2)
void conv_lds(const unsigned short* __restrict__ xb, const unsigned short* __restrict__ wb,
              const float* __restrict__ bias, float* __restrict__ out) {
    __shared__ __align__(16) short lds[2][4 * SLABS];   // 82944 B
    int bid = blockIdx.x;
    int tid = threadIdx.x, lane = tid & 63, wave = tid >> 6;
    int zs = wave >> 1, mh = wave & 1;
    int col = lane & 15, kl = lane >> 4;

    int b = bid >> 6, k = bid & 63;
    int start, cntt;
    if (k < 48) { start = k * 7; cntt = 7; }
    else        { start = 336 + (k - 48) * 6; cntt = 6; }

    const unsigned short* xbb = xb + (size_t)b * PD3 * 32;

    // ---- W prologue: 27 taps for this mh, asm-forced resident ----
    const unsigned short* wgl = wb + (size_t)b * 27648 + mh * 512 + lane * 8;
    short8 wreg[27];
#pragma unroll
    for (int t27 = 0; t27 < 27; ++t27) {
        const unsigned short* p = wgl + (size_t)t27 * 1024;
        asm volatile("global_load_dwordx4 %0, %1, off" : "=v"(wreg[t27]) : "v"(p));
    }

    // staging: 8 waves cover 2592 16B-chunks (wave: slab w>>1, half w&1)
    int sl = wave >> 1, hbase = (wave & 1) * 324;
    auto stage = [&](int tau, int buf) {
        int txx = tau % 3, tyy = (tau / 3) % 12, tzz = tau / 36;
        const unsigned short* base = xbb +
            ((size_t)(tzz * 4) * PD2 + (size_t)(tyy * 4) * PD + txx * 16) * 32 + sl * 8;
#pragma unroll
        for (int kk = 0; kk < 6; ++kk) {
            int h0 = hbase + kk * 64;
            int h  = h0 + lane;
            if (h < hbase + 324) {
                int hz = h / 108, rem = h % 108, hy = rem / 18, hx = rem % 18;
                __builtin_amdgcn_global_load_lds(
                    (const unsigned int*)(base + ((size_t)hz * PD2 + hy * PD + hx) * 32),
                    (unsigned int*)&lds[buf][sl * SLABS + h0 * 8], 16, 0, 0);
            }
        }
    };

    stage(start, 0);
    __syncthreads();    // drains W loads + stage0

    for (int i = 0; i < cntt; ++i) {
        int tau = start + i;
        if (i + 1 < cntt) stage(tau + 1, (i + 1) & 1);

        int txx = tau % 3, tyy = (tau / 3) % 12, tzz = tau / 36;
        const short* lbase = &lds[i & 1][kl * SLABS + (zs * 108 + col) * 8];

        f32x4 acc[4];
#pragma unroll
        for (int r = 0; r < 4; ++r)
#pragma unroll
            for (int e = 0; e < 4; ++e) acc[r][e] = 0.0f;

#pragma unroll
        for (int kz = 0; kz < 3; ++kz)
#pragma unroll
            for (int kx = 0; kx < 3; ++kx) {
                const short* lb = lbase + (kz * 108 + kx) * 8;
                short8 bfv[6];
#pragma unroll
                for (int u = 0; u < 6; ++u)
                    bfv[u] = *(const short8*)(lb + u * 144);
#pragma unroll
                for (int ky = 0; ky < 3; ++ky) {
                    short8 a = wreg[(kz * 3 + kx) * 3 + ky];
#pragma unroll
                    for (int r = 0; r < 4; ++r)
                        acc[r] = __builtin_amdgcn_mfma_f32_16x16x32_bf16(a, bfv[r + ky], acc[r], 0, 0, 0);
                }
            }

        int xc = txx * 16 + col;
        int z  = tzz * 4 + zs;
        int m0 = kl * 4 + mh * 16;
        int o = m0 >> 3, bk0 = m0 & 7;
        float bi = (bk0 == 0) ? bias[o] : 0.0f;
#pragma unroll
        for (int r = 0; r < 4; ++r) {
            int y = tyy * 4 + r;
            int vox = (z * 48 + y) * 48 + xc;
            f32x4 v = acc[r];
            v[0] += bi;
            *(f32x4*)(out + (((size_t)(b * 4 + o)) * S3 + vox) * 8 + bk0) = v;
        }
        if (i + 1 < cntt) {
            // retire the 6 stage loads (oldest in FIFO); let the 4 stores fly
            asm volatile("s_waitcnt vmcnt(4)" ::: "memory");
            __builtin_amdgcn_s_barrier();
            __builtin_amdgcn_sched_barrier(0);
        }
    }
}

// ---------------- host ------------------------------------------------------
static inline int pc_host(int v) { return __builtin_popcount(v); }

extern "C" void kernel_launch(void* const* d_in, const int* in_sizes, int n_in,
                              void* d_out, int out_size, void* d_ws, size_t ws_size,
                              hipStream_t stream) {
    const float* x    = (const float*)d_in[0];
    const float* w0   = (const float*)d_in[1];
    const float* b0   = (const float*)d_in[2];
    const float* w1   = (const float*)d_in[3];
    const float* b1   = (const float*)d_in[4];
    const float* w2   = (const float*)d_in[5];
    const float* b2   = (const float*)d_in[6];
    const float* bias = (const float*)d_in[7];
    float* out = (float*)d_out;

    float* ws      = (float*)d_ws;
    float* partial = ws;                                     // 16384 floats
    unsigned short* wbb = (unsigned short*)(ws + 30272);     // bf16 W, 110592 shorts
    unsigned short* xb  = wbb + 110592;                      // padded bf16 x, 32 MB

    int cnt = 0;
    for (int z = 0; z < SS; ++z) {
        int dz = 2 * z - 47;
        for (int y = 0; y < SS; ++y) {
            int dy = 2 * y - 47;
            for (int xx = 0; xx < SS; ++xx) {
                int dx = 2 * xx - 47;
                if (dx * dx + dy * dy + dz * dz <= 2209) ++cnt;
            }
        }
    }
    float inv_norm = 1.0f / ((float)cnt * (float)CIN);

    int pidtab[4][4][4];
    {
        bool ex[4][4][4] = {};
        for (int A = 0; A < 8; ++A)
            for (int B = 0; B < 8; ++B)
                ex[pc_host(A)][pc_host(B)][pc_host(A ^ B)] = true;
        int p = 0;
        for (int gi = 0; gi < 4; ++gi)
            for (int gj = 0; gj < 4; ++gj)
                for (int gk = 0; gk < 4; ++gk)
                    pidtab[gi][gj][gk] = ex[gi][gj][gk] ? p++ : -1;
    }
    static const int blades[8] = {0, 1, 2, 4, 3, 5, 6, 7};
    Tables tb;
    for (int bj = 0; bj < 8; ++bj) {
        for (int bk = 0; bk < 8; ++bk) {
            int bmj = blades[bj], bmk = blades[bk];
            int bma = bmj ^ bmk;
            int sgn = 1, t = bma >> 1;
            while (t) {
                if (pc_host(t & bmj) & 1) sgn = -sgn;
                t >>= 1;
            }
            tb.sgn[bj * 8 + bk] = (float)sgn;
            tb.pid[bj * 8 + bk] = pidtab[pc_host(bma)][pc_host(bmj)][pc_host(bmk)];
        }
    }

    pack_cond_kernel<<<dim3(489, BATCH), dim3(256), 0, stream>>>(x, xb, partial);
    mlp_fused<<<dim3(BATCH * XT), dim3(320), 0, stream>>>(partial, w0, b0, w1, b1, w2, b2,
                                                          wbb, inv_norm, tb);
    conv_lds<<<dim3(256), dim3(512), 0, stream>>>(xb, wbb, bias, out);
}